// Round 3
// baseline (185.555 us; speedup 1.0000x reference)
//
#include <hip/hip_runtime.h>
#include <math.h>

// Problem constants (match the jax reference)
constexpr int B_  = 2;
constexpr int C_  = 64;
constexpr int HW_ = 64 * 128;      // 8192
constexpr int N_  = HW_;           // points per image (near == far == 8192)
constexpr int NX_ = 512;
constexpr int NY_ = 512;
constexpr int NYNX_ = NX_ * NY_;   // 262144
constexpr int GC_  = 32;           // NN search grid is GC x GC cells of 1.6 m
constexpr int GCC_ = GC_ * GC_;    // 1024 cells
constexpr int CAP_ = 48;           // max pts per NN cell (Poisson(4), P(>=48)~1e-40)
constexpr int LPF_ = 8;            // lanes per far point in nn_search
constexpr int BN_  = B_ * N_;      // 16384
constexpr int NNB_ = BN_ / (256 / LPF_);   // 512 NN blocks (32 far pts/block)
constexpr int NSB_ = BN_ / 32;             // 512 near-scatter blocks (32 pts/block)
constexpr int MAXSLOT_ = 32768;    // >= max occupied voxels (<= BN_ touches)

// ---------------------------------------------------------------------------
// Shared voxel binning (numpy f32 bitwise). -1 = contributes nothing.
// ---------------------------------------------------------------------------
__device__ __forceinline__ int voxel_of(float x, float y, float w) {
#pragma clang fp contract(off)
  if (w == 0.0f) return -1;
  float qx = (x - 0.0f) / 0.1f;
  float qy = (y - (-25.6f)) / 0.1f;
  int ix = (int)floorf(qx);
  int iy = (int)floorf(qy);
  if (ix < 0 || ix >= NX_ || iy < 0 || iy >= NY_) return -1;
  return iy * NX_ + ix;
}

// NN-grid cell coords (internal only — must be identical in build & search).
__device__ __forceinline__ int gcell_x(float x) {
  int c = (int)floorf(x * 0.625f);          // /1.6
  return min(GC_ - 1, max(0, c));
}
__device__ __forceinline__ int gcell_y(float y) {
  int c = (int)floorf((y + 25.6f) * 0.625f);
  return min(GC_ - 1, max(0, c));
}

// Wave-aggregated slot allocation: one atomic per wave (leader), slots dense.
// Called in divergent context; __ballot gives the active mask.
__device__ __forceinline__ int alloc_slot(int* nslot) {
  unsigned long long mk = __ballot(1);
  int lane = threadIdx.x & 63;
  int lead = __ffsll((unsigned long long)mk) - 1;
  int nact = __popcll(mk);
  int basep = 0;
  if (lane == lead) basep = atomicAdd(nslot, nact);
  basep = __shfl(basep, lead);
  return basep + __popcll(mk & ((1ull << lane) - 1ull));
}

// ---------------------------------------------------------------------------
// Fused prep: blocks [0,64) pack+count points, bucket valid near points into
// fixed-capacity NN cells (gpts/gidx at cell*CAP_ + slot via the histogram
// atomic), count voxel hits in cnt, and on each voxel's 0->1 transition
// allocate a COMPACT acc slot (slotmap[kv] = slot+1). acc itself is only
// MAXSLOT_*256 B = 8 MB, pre-zeroed by the launch memset, so no row-zeroing
// is needed anywhere and scatters stay L2-resident.
// Within-cell bucket order is arbitrary (atomic race) — selection is
// lexicographic, so results are bit-exact.
// Blocks [64,320) transpose fv (B,C,HW) -> fvT (B,HW,C). Halves independent.
// ---------------------------------------------------------------------------
__global__ __launch_bounds__(256) void prep_kernel(
    const float* __restrict__ fv,
    const float* __restrict__ pi, const int* __restrict__ pm,
    const float* __restrict__ pif, const int* __restrict__ pmf,
    float4* __restrict__ near4, float4* __restrict__ far4,
    float* __restrict__ cnt, int* __restrict__ gcellcnt,
    int* __restrict__ nslot, int* __restrict__ slotmap,
    float4* __restrict__ gpts, int* __restrict__ gidx,
    float* __restrict__ fvT) {
#pragma clang fp contract(off)
  __shared__ float tile[64][65];
  if (blockIdx.x < 64) {
    // ---- pack + count + bucket fill + slot alloc ----
    int t = blockIdx.x * 256 + threadIdx.x;        // over B_*N_
    int k = t / N_, n = t % N_;
    const float* base  = pi  + (size_t)k * 4 * HW_;
    const float* basef = pif + (size_t)k * 4 * HW_;
    float x = base[n], y = base[HW_ + n], z = base[2 * HW_ + n];
    bool v = pm[k * HW_ + n] > 0;
    near4[t] = make_float4(x, y, z, v ? 1.0f : 0.0f);
    float fx = basef[n], fy = basef[HW_ + n], fz = basef[2 * HW_ + n];
    bool vf = pmf[k * HW_ + n] > 0;
    far4[t] = make_float4(fx, fy, fz, vf ? 1.0f : 0.0f);

    // valid near points -> NN cell bucket (slot from histogram atomic)
    if (v) {
      float sq = (x * x + y * y) + z * z;   // numpy 3-elem sum order
      int c = gcell_y(y) * GC_ + gcell_x(x);
      int p = atomicAdd(&gcellcnt[k * GCC_ + c], 1);
      if (p < CAP_) {
        size_t o = (size_t)(k * GCC_ + c) * CAP_ + p;
        gpts[o] = make_float4(x, y, z, sq);
        gidx[o] = n;
      }
    }

    int vn = voxel_of(x, y, v ? 1.0f : 0.0f);
    if (vn >= 0) {
      int kv = k * NYNX_ + vn;
      float old = atomicAdd(&cnt[kv], 1.0f);
      if (old == 0.0f) slotmap[kv] = alloc_slot(nslot) + 1;
    }
    int vfv = voxel_of(fx, fy, vf ? 1.0f : 0.0f);
    if (vfv >= 0) {
      int kv = k * NYNX_ + vfv;
      float old2 = atomicAdd(&cnt[kv], 1.0f);
      if (old2 == 0.0f) slotmap[kv] = alloc_slot(nslot) + 1;
    }
  } else {
    // ---- transpose ----
    int bid = blockIdx.x - 64;          // 0..255
    int k = bid >> 7;                   // /128
    int n0 = (bid & 127) * 64;
    int tx = threadIdx.x & 63, ty = threadIdx.x >> 6;
    for (int c = ty; c < C_; c += 4)
      tile[c][tx] = fv[((size_t)(k * C_ + c)) * HW_ + n0 + tx];
    __syncthreads();
    for (int nn = ty; nn < 64; nn += 4)
      fvT[((size_t)(k * HW_ + n0 + nn)) * C_ + tx] = tile[tx][nn];
  }
}

// ---------------------------------------------------------------------------
// Lexicographic stable top-3 insert on (value, index): lower value wins,
// ties broken by lower index. Order-INDEPENDENT (safe for arbitrary candidate
// order) and equal to jax stable top-k. Invariant: slots lex-sorted.
// ---------------------------------------------------------------------------
__device__ __forceinline__ void merge3L(float tv, int idx,
                                        float& b0, float& b1, float& b2,
                                        int& i0, int& i1, int& i2) {
  bool w0 = (tv < b0) || (tv == b0 && idx < i0);
  bool w1 = (tv < b1) || (tv == b1 && idx < i1);
  bool w2 = (tv < b2) || (tv == b2 && idx < i2);
  float ob0 = b0, ob1 = b1;
  int   oi0 = i0, oi1 = i1;
  b0 = w0 ? tv : b0;                    i0 = w0 ? idx : i0;
  b1 = w0 ? ob0 : (w1 ? tv : b1);       i1 = w0 ? oi0 : (w1 ? idx : i1);
  b2 = w1 ? ob1 : (w2 ? tv : b2);       i2 = w1 ? oi1 : (w2 ? idx : i2);
}

// ---------------------------------------------------------------------------
// Fused NN + scatter into the COMPACT acc (slot indirection via slotmap).
// Blocks [0, NNB_): exact 3-NN (expanding Chebyshev rings, 8 lanes/far) then
// the SAME octet gathers the three fvT rows (float4, coalesced) and writes
// the interpolated 256 B acc row ((i,w) broadcast in-register via shfl,
// bit-exact). Invalid far points (~50%) early-return (octet-uniform).
// Value expr identical: (w0*a + w1*b) + w2*c, contract off.
// Blocks [NNB_, NNB_+NSB_): near-point scatter, ALSO octet-style — 8 lanes
// per point, 2 float4 chunks each (vectorized; 8x fewer waves than
// wave-per-point). cnt==1 rows (98%) are plain stores; cnt>=2 rows atomics.
// ---------------------------------------------------------------------------
__global__ __launch_bounds__(256) void nn_scatter_kernel(
    const float4* __restrict__ far4, const int* __restrict__ gcellcnt,
    const float4* __restrict__ gpts, const int* __restrict__ gidx,
    const float4* __restrict__ near4, const float* __restrict__ fvT,
    const float* __restrict__ cnt, const int* __restrict__ slotmap,
    float* __restrict__ acc) {
#pragma clang fp contract(off)
  int tid = threadIdx.x;
  if (blockIdx.x < (unsigned)NNB_) {
    int q = tid & (LPF_ - 1);
    int g = blockIdx.x * (256 / LPF_) + (tid / LPF_);   // far point id over BN
    int k = g >> 13;                        // /8192
    int m = g & (N_ - 1);

    float4 f = far4[k * N_ + m];
    if (f.w == 0.0f) return;   // invalid far point: octet-uniform, no output

    float sf = (f.x * f.x + f.y * f.y) + f.z * f.z;   // numpy 3-elem order
    float ax = 2.0f * f.x, ay = 2.0f * f.y, az = 2.0f * f.z;
    int fcx = gcell_x(f.x), fcy = gcell_y(f.y);
    const int* gcc_ = gcellcnt + k * GCC_;

    float b0 = 1e30f, b1 = 1e30f, b2 = 1e30f;
    int i0 = 0, i1 = 0, i2 = 0;

    for (int r = 0; r < GC_; ++r) {
      int nc = (r == 0) ? 1 : 8 * r;
      for (int i = q; i < nc; i += LPF_) {
        int dx, dy;
        if (r == 0)            { dx = 0;             dy = 0; }
        else if (i < 2*r + 1)  { dx = i - r;         dy = -r; }
        else if (i < 4*r + 2)  { dx = i - (3*r + 1); dy = r; }
        else if (i < 6*r + 1)  { dx = -r;            dy = i - (5*r + 1); }
        else                   { dx = r;             dy = i - 7*r; }
        int cx = fcx + dx, cy = fcy + dy;
        if (cx < 0 || cx >= GC_ || cy < 0 || cy >= GC_) continue;
        int c = cy * GC_ + cx;
        int e = gcc_[c];
        if (e > CAP_) e = CAP_;
        const float4* gp = gpts + (size_t)(k * GCC_ + c) * CAP_;
        const int*    gi = gidx + (size_t)(k * GCC_ + c) * CAP_;
        for (int j = 0; j < e; ++j) {
          float4 p = gp[j];
          int idx = gi[j];
          float p0 = ax * p.x;                                  // round(ax*px)
          float mm = __builtin_fmaf(az, p.z, __builtin_fmaf(ay, p.y, p0));
          float tv = (sf + p.w) - mm;
          merge3L(tv, idx, b0, b1, b2, i0, i1, i2);
        }
      }
      // octet-shared conservative bound (min of lanes' 3rd-best; 1e30 until
      // some lane holds 3 -> keep expanding, always safe)
      float s2 = b2;
      s2 = fminf(s2, __shfl_xor(s2, 1));
      s2 = fminf(s2, __shfl_xor(s2, 2));
      s2 = fminf(s2, __shfl_xor(s2, 4));
      float rd = (float)r * 1.6f;
      if (rd * rd > s2 + 0.01f) break;
    }

    // octet merge on lane 0 (lexicographic, order-independent)
    int base = tid & ~(LPF_ - 1);
    for (int s = 1; s < LPF_; ++s) {
      float v0 = __shfl(b0, base + s), v1 = __shfl(b1, base + s), v2 = __shfl(b2, base + s);
      int   j0 = __shfl(i0, base + s), j1 = __shfl(i1, base + s), j2 = __shfl(i2, base + s);
      if (q == 0) {
        merge3L(v0, j0, b0, b1, b2, i0, i1, i2);
        merge3L(v1, j1, b0, b1, b2, i0, i1, i2);
        merge3L(v2, j2, b0, b1, b2, i0, i1, i2);
      }
    }
    // weights on lane 0 (exactly as reference), then broadcast bit-exact
    float w0_ = 0.0f, w1_ = 0.0f, w2_ = 0.0f;
    if (q == 0) {
      float r0 = 1.0f / (b0 + 1e-8f);
      float r1 = 1.0f / (b1 + 1e-8f);
      float r2 = 1.0f / (b2 + 1e-8f);
      float rs = (r0 + r1) + r2;
      w0_ = r0 / rs; w1_ = r1 / rs; w2_ = r2 / rs;
    }
    float w0 = __shfl(w0_, base), w1 = __shfl(w1_, base), w2 = __shfl(w2_, base);
    int   j0 = __shfl(i0, base),  j1 = __shfl(i1, base),  j2 = __shfl(i2, base);

    // far-point scatter: octet handles the 64-channel row, lane q owns
    // float4 chunks {2q, 2q+1} (coalesced 256 B per row).
    int v = voxel_of(f.x, f.y, f.w);
    if (v < 0) return;
    int kv = k * NYNX_ + v;
    float cn = cnt[kv];
    size_t rowoff = (size_t)(slotmap[kv] - 1) * C_;
    const float4* r0p = (const float4*)(fvT + ((size_t)(k * N_ + j0)) * C_);
    const float4* r1p = (const float4*)(fvT + ((size_t)(k * N_ + j1)) * C_);
    const float4* r2p = (const float4*)(fvT + ((size_t)(k * N_ + j2)) * C_);
#pragma unroll
    for (int h = 0; h < 2; ++h) {
      int c4 = q * 2 + h;
      float4 a = r0p[c4], b = r1p[c4], c = r2p[c4];
      float4 val;
      val.x = (w0 * a.x + w1 * b.x) + w2 * c.x;
      val.y = (w0 * a.y + w1 * b.y) + w2 * c.y;
      val.z = (w0 * a.z + w1 * b.z) + w2 * c.z;
      val.w = (w0 * a.w + w1 * b.w) + w2 * c.w;
      if (cn == 1.0f) {
        ((float4*)(acc + rowoff))[c4] = val;
      } else {
        float* p = acc + rowoff + c4 * 4;
        atomicAdd(p + 0, val.x); atomicAdd(p + 1, val.y);
        atomicAdd(p + 2, val.z); atomicAdd(p + 3, val.w);
      }
    }
  } else {
    // ---- near-point scatter: 8 lanes/point, 2 float4 chunks per lane ----
    int q = tid & 7;
    int g = (blockIdx.x - NNB_) * 32 + (tid >> 3);  // point id over BN_
    int k = g >> 13;
    int n = g & (N_ - 1);
    float4 pt = near4[k * N_ + n];
    if (pt.w == 0.0f) return;                        // octet-uniform
    int v = voxel_of(pt.x, pt.y, pt.w);
    if (v < 0) return;
    int kv = k * NYNX_ + v;
    float cn = cnt[kv];                              // octet-uniform
    size_t rowoff = (size_t)(slotmap[kv] - 1) * C_;
    const float4* src = (const float4*)(fvT + ((size_t)(k * N_ + n)) * C_);
#pragma unroll
    for (int h = 0; h < 2; ++h) {
      int c4 = q * 2 + h;
      float4 val = src[c4];
      if (cn == 1.0f) {
        ((float4*)(acc + rowoff))[c4] = val;
      } else {
        float* p = acc + rowoff + c4 * 4;
        atomicAdd(p + 0, val.x); atomicAdd(p + 1, val.y);
        atomicAdd(p + 2, val.z); atomicAdd(p + 3, val.w);
      }
    }
  }
}

// ---------------------------------------------------------------------------
// Emit out (B,C,NY,NX) from compact acc via slotmap + LDS transpose.
// Per block: 64 voxels. Covers every out element exactly once (fuses the
// zero-fill + mean divide).
// ---------------------------------------------------------------------------
__global__ __launch_bounds__(256) void emit_kernel(
    const float* __restrict__ acc, const float* __restrict__ cnt,
    const int* __restrict__ slotmap, float* __restrict__ out) {
#pragma clang fp contract(off)
  __shared__ float tile[64][65];
  __shared__ float cs[64];
  __shared__ int   sl[64];
  int t = threadIdx.x;
  int k = blockIdx.y;
  int v0 = blockIdx.x * 64;

  if (t < 64) {
    cs[t] = cnt[(size_t)k * NYNX_ + v0 + t];
    sl[t] = slotmap[(size_t)k * NYNX_ + v0 + t];
  }
  __syncthreads();

  const float4* acc4 = (const float4*)acc;
#pragma unroll
  for (int p = 0; p < 4; ++p) {
    int row = p * 16 + (t >> 4);     // voxel within block
    int f4  = t & 15;                // float4 within the 64-channel row
    float c = cs[row];
    float4 a = make_float4(0.0f, 0.0f, 0.0f, 0.0f);
    if (c > 0.0f) {
      a = acc4[(size_t)(sl[row] - 1) * (C_ / 4) + f4];
      a.x /= c; a.y /= c; a.z /= c; a.w /= c;
    }
    tile[f4 * 4 + 0][row] = a.x;
    tile[f4 * 4 + 1][row] = a.y;
    tile[f4 * 4 + 2][row] = a.z;
    tile[f4 * 4 + 3][row] = a.w;
  }
  __syncthreads();

#pragma unroll
  for (int p = 0; p < 4; ++p) {
    int c  = p * 16 + (t >> 4);      // channel
    int xq = t & 15;                 // float4 of voxels
    float4 o = make_float4(tile[c][xq * 4 + 0], tile[c][xq * 4 + 1],
                           tile[c][xq * 4 + 2], tile[c][xq * 4 + 3]);
    ((float4*)out)[(((size_t)k * C_ + c) * NYNX_ + v0) / 4 + xq] = o;
  }
}

extern "C" void kernel_launch(void* const* d_in, const int* in_sizes, int n_in,
                              void* d_out, int out_size, void* d_ws, size_t ws_size,
                              hipStream_t stream) {
  const float* fv  = (const float*)d_in[0];  // (B,C,H,W)
  const float* pi  = (const float*)d_in[1];  // (B,4,H,W)
  const int*   pm  = (const int*)d_in[2];    // (B,H,W)
  const float* pif = (const float*)d_in[3];  // (B,4,H,W)
  const int*   pmf = (const int*)d_in[4];    // (B,H,W)
  float* out = (float*)d_out;                // (B,C,NY,NX) f32

  // workspace layout (16B aligned). The region [cnt .. acc] is CONTIGUOUS so
  // ONE memset zeroes cnt + gcellcnt + nslot + slotmap + acc (12.6 MB ~ 2 us).
  char* wsb = (char*)d_ws;
  float*  fvT    = (float*)(wsb);                 // 4,194,304
  float*  cnt    = (float*)(wsb + 4194304);       // 2,097,152
  int*    gcell  = (int*)(wsb + 6291456);         // 8,192
  int*    nslot  = (int*)(wsb + 6299648);         // 16
  int*    slotmap= (int*)(wsb + 6299664);         // 2,097,152
  float*  acc    = (float*)(wsb + 8396816);       // MAXSLOT_*C_*4 = 8,388,608
  float4* near4  = (float4*)(wsb + 16785424);     // 262,144
  float4* far4   = (float4*)(wsb + 17047568);     // 262,144
  float4* gpts   = (float4*)(wsb + 17309712);     // B*GCC*CAP*16 = 1,572,864
  int*    gidx   = (int*)(wsb + 18882576);        // B*GCC*CAP*4  =   393,216
                                                  // end: 19,275,792

  // one memset: cnt + gcell + nslot + slotmap + acc = 12,591,120 B
  hipMemsetAsync(cnt, 0, 12591120, stream);

  prep_kernel<<<320, 256, 0, stream>>>(
      fv, pi, pm, pif, pmf, near4, far4, cnt, gcell, nslot, slotmap,
      gpts, gidx, fvT);
  nn_scatter_kernel<<<NNB_ + NSB_, 256, 0, stream>>>(
      far4, gcell, gpts, gidx, near4, fvT, cnt, slotmap, acc);
  emit_kernel<<<dim3(NYNX_ / 64, B_), 256, 0, stream>>>(acc, cnt, slotmap, out);
}

// Round 4
// 182.363 us; speedup vs baseline: 1.0175x; 1.0175x over previous
//
#include <hip/hip_runtime.h>
#include <math.h>

// Problem constants (match the jax reference)
constexpr int B_  = 2;
constexpr int C_  = 64;
constexpr int HW_ = 64 * 128;      // 8192
constexpr int N_  = HW_;           // points per image (near == far == 8192)
constexpr int NX_ = 512;
constexpr int NY_ = 512;
constexpr int NYNX_ = NX_ * NY_;   // 262144 = 2^18
constexpr int GC_  = 32;           // NN search grid is GC x GC cells of 1.6 m
constexpr int GCC_ = GC_ * GC_;    // 1024 cells
constexpr int CAP_ = 48;           // max pts per NN cell (Poisson(4), P(>=48)~1e-40)
constexpr int LPF_ = 8;            // lanes per far point in nn_search
constexpr int BN_  = B_ * N_;      // 16384
constexpr int NNB_ = BN_ / 32;     // 512 worst-case far-NN blocks (32 pts/block)
constexpr int NSB_ = BN_ / 32;     // 512 worst-case near-scatter blocks

// ---------------------------------------------------------------------------
// Shared voxel binning (numpy f32 bitwise). -1 = contributes nothing.
// ---------------------------------------------------------------------------
__device__ __forceinline__ int voxel_of(float x, float y, float w) {
#pragma clang fp contract(off)
  if (w == 0.0f) return -1;
  float qx = (x - 0.0f) / 0.1f;
  float qy = (y - (-25.6f)) / 0.1f;
  int ix = (int)floorf(qx);
  int iy = (int)floorf(qy);
  if (ix < 0 || ix >= NX_ || iy < 0 || iy >= NY_) return -1;
  return iy * NX_ + ix;
}

// NN-grid cell coords (internal only — must be identical in build & search).
__device__ __forceinline__ int gcell_x(float x) {
  int c = (int)floorf(x * 0.625f);          // /1.6
  return min(GC_ - 1, max(0, c));
}
__device__ __forceinline__ int gcell_y(float y) {
  int c = (int)floorf((y + 25.6f) * 0.625f);
  return min(GC_ - 1, max(0, c));
}

// Wave-aggregated list append: one atomic per wave (leader), dense indices.
// Called in divergent context; __ballot gives the active mask.
__device__ __forceinline__ int wave_append(int* ctr) {
  unsigned long long mk = __ballot(1);
  int lane = threadIdx.x & 63;
  int lead = __ffsll((unsigned long long)mk) - 1;
  int basep = 0;
  if (lane == lead) basep = atomicAdd(ctr, __popcll(mk));
  basep = __shfl(basep, lead);
  return basep + __popcll(mk & ((1ull << lane) - 1ull));
}

// ---------------------------------------------------------------------------
// Fused prep: blocks [0,64) pack points, bucket valid near points into
// fixed-capacity NN cells (gpts/gidx at cell*CAP_ + slot via the histogram
// atomic), count voxel hits in cnt, zero acc rows on the 1->2 cnt transition
// (single detecting thread; all acc scatter writes happen in a later kernel),
// and COMPACT the contributing points into dense lists:
//   farlist  (float4 {x,y,z,bitcast(kv)}) — valid far pts with in-range voxel
//   nearlist (int2  {kv, k*N+n})          — valid near pts with in-range voxel
// so the scatter kernel's waves do only dense work (the ~50% invalid points
// cost zero waves there instead of a per-octet early-out that rarely retires
// a whole wave). Within-cell/list order is arbitrary (atomic race) —
// selection is lexicographic and scatter is order-independent per row type,
// so results match the reference bit-for-bit (same absmax as prior rounds).
// Blocks [64,320) transpose fv (B,C,HW) -> fvT (B,HW,C). Halves independent.
// ---------------------------------------------------------------------------
__global__ __launch_bounds__(256) void prep_kernel(
    const float* __restrict__ fv,
    const float* __restrict__ pi, const int* __restrict__ pm,
    const float* __restrict__ pif, const int* __restrict__ pmf,
    float* __restrict__ cnt, int* __restrict__ gcellcnt,
    int* __restrict__ nctr, float4* __restrict__ farlist,
    int2* __restrict__ nearlist,
    float4* __restrict__ gpts, int* __restrict__ gidx,
    float* __restrict__ acc, float* __restrict__ fvT) {
#pragma clang fp contract(off)
  __shared__ float tile[64][65];
  if (blockIdx.x < 64) {
    // ---- pack + count + bucket fill + compaction ----
    int t = blockIdx.x * 256 + threadIdx.x;        // over B_*N_
    int k = t / N_, n = t % N_;
    const float* base  = pi  + (size_t)k * 4 * HW_;
    const float* basef = pif + (size_t)k * 4 * HW_;
    float x = base[n], y = base[HW_ + n], z = base[2 * HW_ + n];
    bool v = pm[k * HW_ + n] > 0;
    float fx = basef[n], fy = basef[HW_ + n], fz = basef[2 * HW_ + n];
    bool vf = pmf[k * HW_ + n] > 0;

    // valid near points -> NN cell bucket (slot from histogram atomic)
    if (v) {
      float sq = (x * x + y * y) + z * z;   // numpy 3-elem sum order
      int c = gcell_y(y) * GC_ + gcell_x(x);
      int p = atomicAdd(&gcellcnt[k * GCC_ + c], 1);
      if (p < CAP_) {
        size_t o = (size_t)(k * GCC_ + c) * CAP_ + p;
        gpts[o] = make_float4(x, y, z, sq);
        gidx[o] = n;
      }
    }

    float4 z4 = make_float4(0.0f, 0.0f, 0.0f, 0.0f);
    int vn = voxel_of(x, y, v ? 1.0f : 0.0f);
    if (vn >= 0) {
      int kv = k * NYNX_ + vn;
      float old = atomicAdd(&cnt[kv], 1.0f);
      if (old == 1.0f) {            // exactly one thread sees the 1->2 step
        float4* row = (float4*)(acc + (size_t)kv * C_);
#pragma unroll
        for (int i = 0; i < C_ / 4; ++i) row[i] = z4;
      }
      int p = wave_append(&nctr[1]);
      nearlist[p] = make_int2(kv, t);
    }
    int vfv = voxel_of(fx, fy, vf ? 1.0f : 0.0f);
    if (vfv >= 0) {
      int kv = k * NYNX_ + vfv;
      float old2 = atomicAdd(&cnt[kv], 1.0f);
      if (old2 == 1.0f) {
        float4* row = (float4*)(acc + (size_t)kv * C_);
#pragma unroll
        for (int i = 0; i < C_ / 4; ++i) row[i] = z4;
      }
      int p = wave_append(&nctr[0]);
      farlist[p] = make_float4(fx, fy, fz, __int_as_float(kv));
    }
  } else {
    // ---- transpose ----
    int bid = blockIdx.x - 64;          // 0..255
    int k = bid >> 7;                   // /128
    int n0 = (bid & 127) * 64;
    int tx = threadIdx.x & 63, ty = threadIdx.x >> 6;
    for (int c = ty; c < C_; c += 4)
      tile[c][tx] = fv[((size_t)(k * C_ + c)) * HW_ + n0 + tx];
    __syncthreads();
    for (int nn = ty; nn < 64; nn += 4)
      fvT[((size_t)(k * HW_ + n0 + nn)) * C_ + tx] = tile[tx][nn];
  }
}

// ---------------------------------------------------------------------------
// Lexicographic stable top-3 insert on (value, index): lower value wins,
// ties broken by lower index. Order-INDEPENDENT (safe for arbitrary candidate
// order) and equal to jax stable top-k. Invariant: slots lex-sorted.
// ---------------------------------------------------------------------------
__device__ __forceinline__ void merge3L(float tv, int idx,
                                        float& b0, float& b1, float& b2,
                                        int& i0, int& i1, int& i2) {
  bool w0 = (tv < b0) || (tv == b0 && idx < i0);
  bool w1 = (tv < b1) || (tv == b1 && idx < i1);
  bool w2 = (tv < b2) || (tv == b2 && idx < i2);
  float ob0 = b0, ob1 = b1;
  int   oi0 = i0, oi1 = i1;
  b0 = w0 ? tv : b0;                    i0 = w0 ? idx : i0;
  b1 = w0 ? ob0 : (w1 ? tv : b1);       i1 = w0 ? oi0 : (w1 ? idx : i1);
  b2 = w1 ? ob1 : (w2 ? tv : b2);       i2 = w1 ? oi1 : (w2 ? idx : i2);
}

// ---------------------------------------------------------------------------
// Fused NN + scatter over the COMPACTED lists (dense wave work).
// Blocks [0, NNB_): exact 3-NN (expanding Chebyshev rings, 8 lanes/far) on
// farlist[0..nfar); then the SAME octet gathers the three fvT rows (float4,
// coalesced) and writes the interpolated 256 B acc row ((i,w) broadcast
// in-register via shfl, bit-exact). Blocks past nfar/32 retire immediately.
// Value expr identical: (w0*a + w1*b) + w2*c, contract off.
// Blocks [NNB_, NNB_+NSB_): near-point copy/accumulate over nearlist[0..nnear),
// 8 lanes/point, 2 float4 chunks each.
// cnt==1 rows (~98%) are plain stores (single writer); cnt>=2 rows atomics.
// ---------------------------------------------------------------------------
__global__ __launch_bounds__(256) void nn_scatter_kernel(
    const int* __restrict__ nctr,
    const float4* __restrict__ farlist, const int2* __restrict__ nearlist,
    const int* __restrict__ gcellcnt,
    const float4* __restrict__ gpts, const int* __restrict__ gidx,
    const float* __restrict__ fvT,
    const float* __restrict__ cnt, float* __restrict__ acc) {
#pragma clang fp contract(off)
  int tid = threadIdx.x;
  if (blockIdx.x < (unsigned)NNB_) {
    int q = tid & (LPF_ - 1);
    int g = blockIdx.x * (256 / LPF_) + (tid / LPF_);   // compacted far index
    if (g >= nctr[0]) return;            // octet-uniform (list is dense)

    float4 f = farlist[g];
    int kv = __float_as_int(f.w);
    int k = kv >> 18;                    // kv = k*NYNX_ + v, NYNX_ = 2^18

    float sf = (f.x * f.x + f.y * f.y) + f.z * f.z;   // numpy 3-elem order
    float ax = 2.0f * f.x, ay = 2.0f * f.y, az = 2.0f * f.z;
    int fcx = gcell_x(f.x), fcy = gcell_y(f.y);
    const int* gcc_ = gcellcnt + k * GCC_;

    float b0 = 1e30f, b1 = 1e30f, b2 = 1e30f;
    int i0 = 0, i1 = 0, i2 = 0;

    for (int r = 0; r < GC_; ++r) {
      int nc = (r == 0) ? 1 : 8 * r;
      for (int i = q; i < nc; i += LPF_) {
        int dx, dy;
        if (r == 0)            { dx = 0;             dy = 0; }
        else if (i < 2*r + 1)  { dx = i - r;         dy = -r; }
        else if (i < 4*r + 2)  { dx = i - (3*r + 1); dy = r; }
        else if (i < 6*r + 1)  { dx = -r;            dy = i - (5*r + 1); }
        else                   { dx = r;             dy = i - 7*r; }
        int cx = fcx + dx, cy = fcy + dy;
        if (cx < 0 || cx >= GC_ || cy < 0 || cy >= GC_) continue;
        int c = cy * GC_ + cx;
        int e = gcc_[c];
        if (e > CAP_) e = CAP_;
        const float4* gp = gpts + (size_t)(k * GCC_ + c) * CAP_;
        const int*    gi = gidx + (size_t)(k * GCC_ + c) * CAP_;
        for (int j = 0; j < e; ++j) {
          float4 p = gp[j];
          int idx = gi[j];
          float p0 = ax * p.x;                                  // round(ax*px)
          float mm = __builtin_fmaf(az, p.z, __builtin_fmaf(ay, p.y, p0));
          float tv = (sf + p.w) - mm;
          merge3L(tv, idx, b0, b1, b2, i0, i1, i2);
        }
      }
      // octet-shared conservative bound (min of lanes' 3rd-best; 1e30 until
      // some lane holds 3 -> keep expanding, always safe)
      float s2 = b2;
      s2 = fminf(s2, __shfl_xor(s2, 1));
      s2 = fminf(s2, __shfl_xor(s2, 2));
      s2 = fminf(s2, __shfl_xor(s2, 4));
      float rd = (float)r * 1.6f;
      if (rd * rd > s2 + 0.01f) break;
    }

    // octet merge on lane 0 (lexicographic, order-independent)
    int base = tid & ~(LPF_ - 1);
    for (int s = 1; s < LPF_; ++s) {
      float v0 = __shfl(b0, base + s), v1 = __shfl(b1, base + s), v2 = __shfl(b2, base + s);
      int   j0 = __shfl(i0, base + s), j1 = __shfl(i1, base + s), j2 = __shfl(i2, base + s);
      if (q == 0) {
        merge3L(v0, j0, b0, b1, b2, i0, i1, i2);
        merge3L(v1, j1, b0, b1, b2, i0, i1, i2);
        merge3L(v2, j2, b0, b1, b2, i0, i1, i2);
      }
    }
    // weights on lane 0 (exactly as reference), then broadcast bit-exact
    float w0_ = 0.0f, w1_ = 0.0f, w2_ = 0.0f;
    if (q == 0) {
      float r0 = 1.0f / (b0 + 1e-8f);
      float r1 = 1.0f / (b1 + 1e-8f);
      float r2 = 1.0f / (b2 + 1e-8f);
      float rs = (r0 + r1) + r2;
      w0_ = r0 / rs; w1_ = r1 / rs; w2_ = r2 / rs;
    }
    float w0 = __shfl(w0_, base), w1 = __shfl(w1_, base), w2 = __shfl(w2_, base);
    int   j0 = __shfl(i0, base),  j1 = __shfl(i1, base),  j2 = __shfl(i2, base);

    // far-point scatter: octet handles the 64-channel row, lane q owns
    // float4 chunks {2q, 2q+1} (coalesced 256 B per row).
    float cn = cnt[kv];
    size_t rowoff = (size_t)kv * C_;
    const float4* r0p = (const float4*)(fvT + ((size_t)(k * N_ + j0)) * C_);
    const float4* r1p = (const float4*)(fvT + ((size_t)(k * N_ + j1)) * C_);
    const float4* r2p = (const float4*)(fvT + ((size_t)(k * N_ + j2)) * C_);
#pragma unroll
    for (int h = 0; h < 2; ++h) {
      int c4 = q * 2 + h;
      float4 a = r0p[c4], b = r1p[c4], c = r2p[c4];
      float4 val;
      val.x = (w0 * a.x + w1 * b.x) + w2 * c.x;
      val.y = (w0 * a.y + w1 * b.y) + w2 * c.y;
      val.z = (w0 * a.z + w1 * b.z) + w2 * c.z;
      val.w = (w0 * a.w + w1 * b.w) + w2 * c.w;
      if (cn == 1.0f) {
        ((float4*)(acc + rowoff))[c4] = val;
      } else {
        float* p = acc + rowoff + c4 * 4;
        atomicAdd(p + 0, val.x); atomicAdd(p + 1, val.y);
        atomicAdd(p + 2, val.z); atomicAdd(p + 3, val.w);
      }
    }
  } else {
    // ---- near-point scatter over nearlist: 8 lanes/pt, 2 float4 each ----
    int q = tid & 7;
    int g = (blockIdx.x - NNB_) * 32 + (tid >> 3);
    if (g >= nctr[1]) return;            // octet-uniform (list is dense)
    int2 e = nearlist[g];
    int kv = e.x;
    float cn = cnt[kv];                  // octet-uniform
    size_t rowoff = (size_t)kv * C_;
    const float4* src = (const float4*)(fvT + (size_t)e.y * C_);
#pragma unroll
    for (int h = 0; h < 2; ++h) {
      int c4 = q * 2 + h;
      float4 val = src[c4];
      if (cn == 1.0f) {
        ((float4*)(acc + rowoff))[c4] = val;
      } else {
        float* p = acc + rowoff + c4 * 4;
        atomicAdd(p + 0, val.x); atomicAdd(p + 1, val.y);
        atomicAdd(p + 2, val.z); atomicAdd(p + 3, val.w);
      }
    }
  }
}

// ---------------------------------------------------------------------------
// Emit out (B,C,NY,NX) from acc/cnt via LDS transpose. Per block: 64 voxels.
// Covers every out element exactly once (fuses the zero-fill + mean divide).
// ---------------------------------------------------------------------------
__global__ __launch_bounds__(256) void emit_kernel(
    const float* __restrict__ acc, const float* __restrict__ cnt,
    float* __restrict__ out) {
#pragma clang fp contract(off)
  __shared__ float tile[64][65];
  __shared__ float cs[64];
  int t = threadIdx.x;
  int k = blockIdx.y;
  int v0 = blockIdx.x * 64;

  if (t < 64) cs[t] = cnt[(size_t)k * NYNX_ + v0 + t];
  __syncthreads();

  const float4* acc4 = (const float4*)acc;
#pragma unroll
  for (int p = 0; p < 4; ++p) {
    int row = p * 16 + (t >> 4);     // voxel within block
    int f4  = t & 15;                // float4 within the 64-channel row
    float c = cs[row];
    float4 a = make_float4(0.0f, 0.0f, 0.0f, 0.0f);
    if (c > 0.0f) {
      a = acc4[((size_t)k * NYNX_ + v0 + row) * (C_ / 4) + f4];
      a.x /= c; a.y /= c; a.z /= c; a.w /= c;
    }
    tile[f4 * 4 + 0][row] = a.x;
    tile[f4 * 4 + 1][row] = a.y;
    tile[f4 * 4 + 2][row] = a.z;
    tile[f4 * 4 + 3][row] = a.w;
  }
  __syncthreads();

#pragma unroll
  for (int p = 0; p < 4; ++p) {
    int c  = p * 16 + (t >> 4);      // channel
    int xq = t & 15;                 // float4 of voxels
    float4 o = make_float4(tile[c][xq * 4 + 0], tile[c][xq * 4 + 1],
                           tile[c][xq * 4 + 2], tile[c][xq * 4 + 3]);
    ((float4*)out)[(((size_t)k * C_ + c) * NYNX_ + v0) / 4 + xq] = o;
  }
}

extern "C" void kernel_launch(void* const* d_in, const int* in_sizes, int n_in,
                              void* d_out, int out_size, void* d_ws, size_t ws_size,
                              hipStream_t stream) {
  const float* fv  = (const float*)d_in[0];  // (B,C,H,W)
  const float* pi  = (const float*)d_in[1];  // (B,4,H,W)
  const int*   pm  = (const int*)d_in[2];    // (B,H,W)
  const float* pif = (const float*)d_in[3];  // (B,4,H,W)
  const int*   pmf = (const int*)d_in[4];    // (B,H,W)
  float* out = (float*)d_out;                // (B,C,NY,NX) f32

  // workspace layout (16B aligned). cnt, gcellcnt, nctr ADJACENT so one
  // memset zeroes all three. acc (direct-mapped, 134 MB) at +16 MB — its
  // touched rows (~4 MB) stay cache-resident; no pre-zero needed (cnt>=2
  // rows are zeroed inline in prep, cnt==1 rows fully overwritten).
  char* wsb = (char*)d_ws;
  float*  fvT     = (float*)(wsb);                 // 4,194,304
  float*  cnt     = (float*)(wsb + 4194304);       // 2,097,152
  int*    gcell   = (int*)(wsb + 6291456);         // 8,192
  int*    nctr    = (int*)(wsb + 6299648);         // 16 (nfar, nnear, pad)
  float4* farlist = (float4*)(wsb + 6299664);      // BN_*16 = 262,144
  int2*   nearlist= (int2*)(wsb + 6561808);        // BN_*8  = 131,072
  float4* gpts    = (float4*)(wsb + 6692880);      // B*GCC*CAP*16 = 1,572,864
  int*    gidx    = (int*)(wsb + 8265744);         // B*GCC*CAP*4  =   393,216
  float*  acc     = (float*)(wsb + 16777216);      // 134,217,728

  // one memset: cnt + gcell + nctr = 2,105,360 B
  hipMemsetAsync(cnt, 0, 2105360, stream);

  prep_kernel<<<320, 256, 0, stream>>>(
      fv, pi, pm, pif, pmf, cnt, gcell, nctr, farlist, nearlist,
      gpts, gidx, acc, fvT);
  nn_scatter_kernel<<<NNB_ + NSB_, 256, 0, stream>>>(
      nctr, farlist, nearlist, gcell, gpts, gidx, fvT, cnt, acc);
  emit_kernel<<<dim3(NYNX_ / 64, B_), 256, 0, stream>>>(acc, cnt, out);
}